// Round 11
// baseline (254.350 us; speedup 1.0000x reference)
//
#include <hip/hip_runtime.h>

// Problem constants
#define BI    1152   // B*N = 32*36
#define NREG  36
#define DD    2048
#define RR    512
#define KK    1024   // 2*R
#define ZROWS (BI*NREG)        // 41472
#define MBLK  144              // 4 bi, rows interleaved j*4+g
#define NBLK  256
#define ABUF  (MBLK*32)        // 4608 elems (9 KB)
#define BBUF  (NBLK*32)        // 8192 elems (16 KB)
#define BUFE  (ABUF+BBUF)      // 12800 elems = 25 KB per buffer

typedef __bf16 bf16;
typedef __bf16 bf16x8 __attribute__((ext_vector_type(8)));
typedef __bf16 bf16x4 __attribute__((ext_vector_type(4)));
typedef float  f32x4  __attribute__((ext_vector_type(4)));

__device__ __forceinline__ void gl_lds16(const void* g, void* l) {
  __builtin_amdgcn_global_load_lds(
      (const __attribute__((address_space(1))) unsigned int*)g,
      (__attribute__((address_space(3))) unsigned int*)l, 16, 0, 0);
}

// ---------------- fused prep: cvt_mm + transpose_uv + transpose_pt + uvcoord -------
__global__ void k_prep(const float* __restrict__ mm, const float* __restrict__ coords,
                       const float* __restrict__ U_feat, const float* __restrict__ V_feat,
                       const float* __restrict__ P_feat, const float* __restrict__ U_coord,
                       const float* __restrict__ V_coord, const float* __restrict__ P_coord,
                       bf16* __restrict__ mmb, bf16* __restrict__ UT, bf16* __restrict__ VT,
                       bf16* __restrict__ PTt, float* __restrict__ uc, float* __restrict__ vc) {
  __shared__ float tile[32][33];
  int bid = blockIdx.x, tid = threadIdx.x;
  if (bid < 2304) {
    int i = bid * 256 + tid;
    float4 v = ((const float4*)mm)[i];
    bf16x4 o = {(bf16)v.x, (bf16)v.y, (bf16)v.z, (bf16)v.w};
    ((bf16x4*)mmb)[i] = o;
  } else if (bid < 4352) {
    int rel = bid - 2304;
    int zz = rel >> 10, rr = rel & 1023;
    int c0 = (rr & 15) * 32, r0 = (rr >> 4) * 32;     // cols 512, rows 2048
    const float* in = zz ? V_feat : U_feat;
    bf16* outp = zz ? VT : UT;
    int tx = tid & 31, ty = tid >> 5;
#pragma unroll
    for (int k = 0; k < 4; k++)
      tile[ty + 8 * k][tx] = in[(long)(r0 + ty + 8 * k) * 512 + c0 + tx];
    __syncthreads();
#pragma unroll
    for (int k = 0; k < 4; k++)
      outp[(long)(c0 + ty + 8 * k) * 2048 + r0 + tx] = (bf16)tile[tx][ty + 8 * k];
  } else if (bid < 6400) {
    int rel = bid - 4352;
    int zz = rel >> 10, rr = rel & 1023;
    int c0 = (rr & 63) * 32, r0 = (rr >> 6) * 32;     // cols 2048, rows 512
    const float* in = zz ? P_feat : P_coord;
    int koff = zz * 512;
    int tx = tid & 31, ty = tid >> 5;
#pragma unroll
    for (int k = 0; k < 4; k++)
      tile[ty + 8 * k][tx] = in[(long)(r0 + ty + 8 * k) * 2048 + c0 + tx];
    __syncthreads();
    int kc = (koff + r0) >> 5;
#pragma unroll
    for (int k = 0; k < 4; k++) {
      int d = c0 + ty + 8 * k;
      PTt[((long)kc * 2048 + d) * 32 + tx] = (bf16)tile[tx][ty + 8 * k];
    }
  } else {
    int g = bid - 6400;
    float c0 = coords[g * 4 + 0], c1 = coords[g * 4 + 1];
    float c2 = coords[g * 4 + 2], c3 = coords[g * 4 + 3];
#pragma unroll
    for (int i = 0; i < 2; i++) {
      int r = tid + i * 256;
      uc[g * RR + r] = c0 * U_coord[r] + c1 * U_coord[RR + r] + c2 * U_coord[2 * RR + r] + c3 * U_coord[3 * RR + r];
      vc[g * RR + r] = c0 * V_coord[r] + c1 * V_coord[RR + r] + c2 * V_coord[2 * RR + r] + c3 * V_coord[3 * RR + r];
    }
  }
}

// ------- stage 3: uf/vf partials (split-K=4), 64x128 tile, dbuf -------
// grid (18, 4, 8): z = uv*4 + kh. Each block does K in [kh*512, kh*512+512).
__launch_bounds__(256)
__global__ void k_gemm_uv(const bf16* __restrict__ mmb, const bf16* __restrict__ UT,
                          const bf16* __restrict__ VT, float* __restrict__ ufp,
                          float* __restrict__ vfp) {
  __shared__ bf16 lds2[2][6144];   // per buf: A 64x32 (2048) + B 128x32 (4096)
  int uv = blockIdx.z >> 2, kh = blockIdx.z & 3;
  const bf16* Bmat = uv ? VT : UT;
  float* outp = (uv ? vfp : ufp) + (long)kh * (BI * RR);
  int m0 = blockIdx.x * 64, n0 = blockIdx.y * 128;
  int kbase = kh * 512;
  int tid = threadIdx.x, wave = tid >> 6, lane = tid & 63;
  int l15 = lane & 15, qv = lane >> 4;
  int qp_c = qv ^ ((l15 >> 1) & 3);
  int qs = (lane & 3) ^ ((lane >> 3) & 3);

  const bf16* gA = mmb + (long)(m0 + wave * 16 + (lane >> 2)) * 2048 + kbase + qs * 8;
  const bf16* gB = Bmat + (long)(n0 + wave * 32 + (lane >> 2)) * 2048 + kbase + qs * 8;
  int lA = wave * 512;
  int lB = 2048 + wave * 1024;

  auto stage = [&](int buf, int k0) {
    bf16* db = &lds2[buf][0];
    gl_lds16(gA + k0, db + lA);
    gl_lds16(gB + k0, db + lB);
    gl_lds16(gB + 16 * 2048 + k0, db + lB + 512);
  };

  f32x4 acc[4][2] = {};
  stage(0, 0);
  for (int k0 = 0; k0 < 512; k0 += 32) {
    int cur = (k0 >> 5) & 1;
    __syncthreads();
    if (k0 + 32 < 512) stage(cur ^ 1, k0 + 32);
    bf16x8 a[4], b[2];
#pragma unroll
    for (int mt = 0; mt < 4; mt++)
      a[mt] = *(const bf16x8*)(&lds2[cur][0] + (mt * 16 + l15) * 32 + qp_c * 8);
#pragma unroll
    for (int nt = 0; nt < 2; nt++)
      b[nt] = *(const bf16x8*)(&lds2[cur][2048] + (wave * 32 + nt * 16 + l15) * 32 + qp_c * 8);
#pragma unroll
    for (int mt = 0; mt < 4; mt++)
#pragma unroll
      for (int nt = 0; nt < 2; nt++)
        acc[mt][nt] = __builtin_amdgcn_mfma_f32_16x16x32_bf16(a[mt], b[nt], acc[mt][nt], 0, 0, 0);
  }
#pragma unroll
  for (int mt = 0; mt < 4; mt++)
#pragma unroll
    for (int nt = 0; nt < 2; nt++)
#pragma unroll
      for (int r = 0; r < 4; r++) {
        int row = m0 + mt * 16 + qv * 4 + r;
        int col = n0 + wave * 32 + nt * 16 + l15;
        outp[(long)row * RR + col] = acc[mt][nt][r];
      }
}

// ------- stage 4: z_t[kc][row'][32], row' = (bi>>2)*144 + j*4 + (bi&3) -------
__global__ void k_build_z(const float* __restrict__ uc, const float* __restrict__ vc,
                          const float* __restrict__ ufp, const float* __restrict__ vfp,
                          bf16* __restrict__ z) {
  __shared__ float uL[36 * 128];
  __shared__ float vL[36 * 128];
  int kq = blockIdx.x, b = blockIdx.y, tid = threadIdx.x;
  int kb = (kq & 3) * 128;
  for (int i = tid; i < 1152; i += 256) {
    int row = i >> 5, kk = (i & 31) * 4;
    long src = (long)(b * 36 + row) * RR + kb + kk;
    float4 u4, v4;
    if (kq < 4) {
      u4 = *(const float4*)(uc + src);
      v4 = *(const float4*)(vc + src);
    } else {
      u4 = make_float4(0.f, 0.f, 0.f, 0.f);
      v4 = make_float4(0.f, 0.f, 0.f, 0.f);
#pragma unroll
      for (int p = 0; p < 4; p++) {
        float4 a1 = *(const float4*)(ufp + (long)p * (BI * RR) + src);
        float4 b1 = *(const float4*)(vfp + (long)p * (BI * RR) + src);
        u4.x += a1.x; u4.y += a1.y; u4.z += a1.z; u4.w += a1.w;
        v4.x += b1.x; v4.y += b1.y; v4.z += b1.z; v4.w += b1.w;
      }
    }
    *(float4*)&uL[row * 128 + kk] = u4;
    *(float4*)&vL[row * 128 + kk] = v4;
  }
  __syncthreads();
  int cbase = blockIdx.z * 20736;
  for (int c = cbase + tid; c < cbase + 20736; c += 256) {
    int kcl = c / 10368;
    int rem = c - kcl * 10368;
    int row = rem >> 3;             // 0..1295 = gl*36 + j
    int x4 = rem & 7;
    int gl = row / 36;
    int j = row - gl * 36;
    int kl = kcl * 32 + x4 * 4;
    float4 u4 = *(const float4*)&uL[gl * 128 + kl];
    float4 v4 = *(const float4*)&vL[j * 128 + kl];
    float x0 = fmaxf(u4.x * v4.x, 0.f), x1 = fmaxf(u4.y * v4.y, 0.f);
    float x2 = fmaxf(u4.z * v4.z, 0.f), x3 = fmaxf(u4.w * v4.w, 0.f);
    bf16x4 o = {(bf16)x0, (bf16)x1, (bf16)x2, (bf16)x3};
    int bi = b * 36 + gl;
    long rowp = (long)(bi >> 2) * 144 + j * 4 + (bi & 3);
    *(bf16x4*)(z + ((long)(kq * 4 + kcl) * ZROWS + rowp) * 32 + x4 * 4) = o;
  }
}

// ---------------- stage 5: main fused GEMM + register max + residual ----------------
// R8 geometry (16x16x32, block 144x256, 4 waves, [row][32]+XOR swizzle, conflicts 0)
// + TRIPLE-buffered LDS with raw s_barrier and manual s_waitcnt vmcnt(N):
// per wave, 6 (waves 0-2) / 7 (wave 3) staging loads per kstep; vmcnt(6|7) before the
// barrier drains stage(k) but keeps stage(k+1) in flight -> each DMA gets ~2 kstep-
// times to land (covers L3 latency) instead of __syncthreads' vmcnt(0) full drain.
// stage(k+2) issued AFTER the barrier (its buffer was last read in kstep k-1, and all
// frag ds_reads retire before the owning wave's barrier arrival via compiler lgkm waits).
__launch_bounds__(256, 2)
__global__ void k_main(const bf16* __restrict__ z, const bf16* __restrict__ PTt,
                       const float* __restrict__ mm, float* __restrict__ out) {
  __shared__ bf16 lds[3 * BUFE];   // 75 KB, 2 blocks/CU -> 150 of 160 KB
  int bid = blockIdx.x;
  int x = bid & 7, t = bid >> 3;
  int dt = t & 7, go = (t >> 3) * 8 + x;   // go 0..287 (4-bi groups)
  int d0 = dt * NBLK;
  int tid = threadIdx.x, wave = tid >> 6, lane = tid & 63;
  int l15 = lane & 15, qv = lane >> 4;
  int qp_c = qv ^ ((l15 >> 1) & 3);
  int qs = (lane & 3) ^ ((lane >> 3) & 3);
  int lroff = (lane >> 2) * 32 + qs * 8;

  // A: 9 segs; wave w -> segs {2w,2w+1}, wave 3 also seg 8. B: wave w -> segs 4w..4w+3.
  const bf16* gA = z + (long)go * ABUF + wave * 1024 + lroff;
  const bf16* gB = PTt + (long)d0 * 32 + wave * 2048 + lroff;
  int lA = wave * 1024;
  int lB = ABUF + wave * 2048;

  auto stage = [&](int buf, int kc) {
    bf16* db = lds + buf * BUFE;
    long ka = (long)kc * (ZROWS * 32L);
    long kb = (long)kc * (2048L * 32);
    gl_lds16(gA + ka, db + lA);
    gl_lds16(gA + ka + 512, db + lA + 512);
    if (wave == 3) gl_lds16(gA + ka + 1024, db + lA + 1024);
    gl_lds16(gB + kb, db + lB);
    gl_lds16(gB + kb + 512, db + lB + 512);
    gl_lds16(gB + kb + 1024, db + lB + 1024);
    gl_lds16(gB + kb + 1536, db + lB + 1536);
  };

  f32x4 acc[9][4] = {};
  stage(0, 0);
  stage(1, 1);
  int buf = 0;
  for (int kc = 0; kc < 32; kc++) {
    // drain stage(kc), keep stage(kc+1) in flight; execution barrier without vmcnt(0)
    if (kc < 31) {
      if (wave == 3) __asm__ volatile("s_waitcnt vmcnt(7)\n\ts_barrier" ::: "memory");
      else           __asm__ volatile("s_waitcnt vmcnt(6)\n\ts_barrier" ::: "memory");
    } else {
      __asm__ volatile("s_waitcnt vmcnt(0)\n\ts_barrier" ::: "memory");
    }
    if (kc + 2 < 32) {
      int bnext = buf + 2; if (bnext >= 3) bnext -= 3;
      stage(bnext, kc + 2);
    }
    const bf16* cur = lds + buf * BUFE;
    bf16x8 b[4];
#pragma unroll
    for (int nt = 0; nt < 4; nt++)
      b[nt] = *(const bf16x8*)(cur + ABUF + (wave * 64 + nt * 16 + l15) * 32 + qp_c * 8);
#pragma unroll
    for (int mt = 0; mt < 9; mt++) {
      bf16x8 av = *(const bf16x8*)(cur + (mt * 16 + l15) * 32 + qp_c * 8);
#pragma unroll
      for (int nt = 0; nt < 4; nt++)
        acc[mt][nt] = __builtin_amdgcn_mfma_f32_16x16x32_bf16(av, b[nt], acc[mt][nt], 0, 0, 0);
    }
    buf++; if (buf >= 3) buf -= 3;
  }

  // epilogue: row-in-block = mt*16 + qv*4 + r = j*4 + g -> g = r, j = mt*4 + qv.
#pragma unroll
  for (int nt = 0; nt < 4; nt++) {
    float mx[4];
#pragma unroll
    for (int r = 0; r < 4; r++) {
      mx[r] = acc[0][nt][r];
#pragma unroll
      for (int mt = 1; mt < 9; mt++) mx[r] = fmaxf(mx[r], acc[mt][nt][r]);
      mx[r] = fmaxf(mx[r], __shfl_xor(mx[r], 16, 64));
      mx[r] = fmaxf(mx[r], __shfl_xor(mx[r], 32, 64));
    }
    if (lane < 16) {
      int col = d0 + wave * 64 + nt * 16 + lane;
#pragma unroll
      for (int r = 0; r < 4; r++) {
        long oa = (long)(go * 4 + r) * DD + col;
        out[oa] = mx[r] + mm[oa];
      }
    }
  }
}

// ---------------- launcher ----------------
extern "C" void kernel_launch(void* const* d_in, const int* in_sizes, int n_in,
                              void* d_out, int out_size, void* d_ws, size_t ws_size,
                              hipStream_t stream) {
  const float* mm     = (const float*)d_in[0];
  const float* coords = (const float*)d_in[1];
  const float* U_feat = (const float*)d_in[2];
  const float* V_feat = (const float*)d_in[3];
  const float* P_feat = (const float*)d_in[4];
  const float* U_coord= (const float*)d_in[5];
  const float* V_coord= (const float*)d_in[6];
  const float* P_coord= (const float*)d_in[7];
  float* out = (float*)d_out;

  char* ws = (char*)d_ws;
  bf16* z   = (bf16*)(ws + 0);                 //  84,934,656 B  [kc][41472 row'][32]
  bf16* PTt = (bf16*)(ws + 84934656);          //   4,194,304 B  [kc][2048][32]
  bf16* mmb = (bf16*)(ws + 89128960);          //   4,718,592 B
  bf16* UT  = (bf16*)(ws + 93847552);          //   2,097,152 B  [512][2048]
  bf16* VT  = (bf16*)(ws + 95944704);          //   2,097,152 B
  float* ufp= (float*)(ws + 98041856);         //   4 x 2,359,296 B (split-K partials)
  float* vfp= (float*)(ws + 107479040);        //   4 x 2,359,296 B
  float* uc = (float*)(ws + 116916224);        //   2,359,296 B
  float* vc = (float*)(ws + 119275520);        // end 121,634,816

  k_prep<<<dim3(7552), dim3(256), 0, stream>>>(mm, coords, U_feat, V_feat, P_feat,
                                               U_coord, V_coord, P_coord,
                                               mmb, UT, VT, PTt, uc, vc);
  k_gemm_uv<<<dim3(18, 4, 8), dim3(256), 0, stream>>>(mmb, UT, VT, ufp, vfp);
  k_build_z<<<dim3(8, 32, 2), dim3(256), 0, stream>>>(uc, vc, ufp, vfp, z);
  k_main<<<dim3(2304), dim3(256), 0, stream>>>(z, PTt, mm, out);
}

// Round 12
// 248.480 us; speedup vs baseline: 1.0236x; 1.0236x over previous
//
#include <hip/hip_runtime.h>

// Problem constants
#define BI    1152   // B*N = 32*36
#define NREG  36
#define DD    2048
#define RR    512
#define KK    1024   // 2*R
#define ZROWS (BI*NREG)        // 41472
#define MBLK  144              // 4 bi, rows interleaved j*4+g
#define NBLK  256
#define ABUF  (MBLK*32)        // 4608 elems (9 KB)
#define BBUF  (NBLK*32)        // 8192 elems (16 KB)
#define BUFE  (ABUF+BBUF)      // 12800 elems = 25 KB per buffer

typedef __bf16 bf16;
typedef __bf16 bf16x8 __attribute__((ext_vector_type(8)));
typedef __bf16 bf16x4 __attribute__((ext_vector_type(4)));
typedef float  f32x4  __attribute__((ext_vector_type(4)));

__device__ __forceinline__ void gl_lds16(const void* g, void* l) {
  __builtin_amdgcn_global_load_lds(
      (const __attribute__((address_space(1))) unsigned int*)g,
      (__attribute__((address_space(3))) unsigned int*)l, 16, 0, 0);
}

// ---------------- fused prep: cvt_mm + transpose_uv + transpose_pt + uvcoord -------
__global__ void k_prep(const float* __restrict__ mm, const float* __restrict__ coords,
                       const float* __restrict__ U_feat, const float* __restrict__ V_feat,
                       const float* __restrict__ P_feat, const float* __restrict__ U_coord,
                       const float* __restrict__ V_coord, const float* __restrict__ P_coord,
                       bf16* __restrict__ mmb, bf16* __restrict__ UT, bf16* __restrict__ VT,
                       bf16* __restrict__ PTt, float* __restrict__ uc, float* __restrict__ vc) {
  __shared__ float tile[32][33];
  int bid = blockIdx.x, tid = threadIdx.x;
  if (bid < 2304) {
    int i = bid * 256 + tid;
    float4 v = ((const float4*)mm)[i];
    bf16x4 o = {(bf16)v.x, (bf16)v.y, (bf16)v.z, (bf16)v.w};
    ((bf16x4*)mmb)[i] = o;
  } else if (bid < 4352) {
    int rel = bid - 2304;
    int zz = rel >> 10, rr = rel & 1023;
    int c0 = (rr & 15) * 32, r0 = (rr >> 4) * 32;     // cols 512, rows 2048
    const float* in = zz ? V_feat : U_feat;
    bf16* outp = zz ? VT : UT;
    int tx = tid & 31, ty = tid >> 5;
#pragma unroll
    for (int k = 0; k < 4; k++)
      tile[ty + 8 * k][tx] = in[(long)(r0 + ty + 8 * k) * 512 + c0 + tx];
    __syncthreads();
#pragma unroll
    for (int k = 0; k < 4; k++)
      outp[(long)(c0 + ty + 8 * k) * 2048 + r0 + tx] = (bf16)tile[tx][ty + 8 * k];
  } else if (bid < 6400) {
    int rel = bid - 4352;
    int zz = rel >> 10, rr = rel & 1023;
    int c0 = (rr & 63) * 32, r0 = (rr >> 6) * 32;     // cols 2048, rows 512
    const float* in = zz ? P_feat : P_coord;
    int koff = zz * 512;
    int tx = tid & 31, ty = tid >> 5;
#pragma unroll
    for (int k = 0; k < 4; k++)
      tile[ty + 8 * k][tx] = in[(long)(r0 + ty + 8 * k) * 2048 + c0 + tx];
    __syncthreads();
    int kc = (koff + r0) >> 5;
#pragma unroll
    for (int k = 0; k < 4; k++) {
      int d = c0 + ty + 8 * k;
      PTt[((long)kc * 2048 + d) * 32 + tx] = (bf16)tile[tx][ty + 8 * k];
    }
  } else {
    int g = bid - 6400;
    float c0 = coords[g * 4 + 0], c1 = coords[g * 4 + 1];
    float c2 = coords[g * 4 + 2], c3 = coords[g * 4 + 3];
#pragma unroll
    for (int i = 0; i < 2; i++) {
      int r = tid + i * 256;
      uc[g * RR + r] = c0 * U_coord[r] + c1 * U_coord[RR + r] + c2 * U_coord[2 * RR + r] + c3 * U_coord[3 * RR + r];
      vc[g * RR + r] = c0 * V_coord[r] + c1 * V_coord[RR + r] + c2 * V_coord[2 * RR + r] + c3 * V_coord[3 * RR + r];
    }
  }
}

// ------- stage 3: uf/vf partials (split-K=2), 64x128 tile, dbuf (R10-proven) -------
__launch_bounds__(256)
__global__ void k_gemm_uv(const bf16* __restrict__ mmb, const bf16* __restrict__ UT,
                          const bf16* __restrict__ VT, float* __restrict__ uf,
                          float* __restrict__ vf, float* __restrict__ uf2,
                          float* __restrict__ vf2) {
  __shared__ bf16 lds2[2][6144];   // per buf: A 64x32 (2048) + B 128x32 (4096)
  int uv = blockIdx.z >> 1, kh = blockIdx.z & 1;
  const bf16* Bmat = uv ? VT : UT;
  float* outp = uv ? (kh ? vf2 : vf) : (kh ? uf2 : uf);
  int m0 = blockIdx.x * 64, n0 = blockIdx.y * 128;
  int kbase = kh * 1024;
  int tid = threadIdx.x, wave = tid >> 6, lane = tid & 63;
  int l15 = lane & 15, qv = lane >> 4;
  int qp_c = qv ^ ((l15 >> 1) & 3);
  int qs = (lane & 3) ^ ((lane >> 3) & 3);

  const bf16* gA = mmb + (long)(m0 + wave * 16 + (lane >> 2)) * 2048 + kbase + qs * 8;
  const bf16* gB = Bmat + (long)(n0 + wave * 32 + (lane >> 2)) * 2048 + kbase + qs * 8;
  int lA = wave * 512;
  int lB = 2048 + wave * 1024;

  auto stage = [&](int buf, int k0) {
    bf16* db = &lds2[buf][0];
    gl_lds16(gA + k0, db + lA);
    gl_lds16(gB + k0, db + lB);
    gl_lds16(gB + 16 * 2048 + k0, db + lB + 512);
  };

  f32x4 acc[4][2] = {};
  stage(0, 0);
  for (int k0 = 0; k0 < 1024; k0 += 32) {
    int cur = (k0 >> 5) & 1;
    __syncthreads();
    if (k0 + 32 < 1024) stage(cur ^ 1, k0 + 32);
    bf16x8 a[4], b[2];
#pragma unroll
    for (int mt = 0; mt < 4; mt++)
      a[mt] = *(const bf16x8*)(&lds2[cur][0] + (mt * 16 + l15) * 32 + qp_c * 8);
#pragma unroll
    for (int nt = 0; nt < 2; nt++)
      b[nt] = *(const bf16x8*)(&lds2[cur][2048] + (wave * 32 + nt * 16 + l15) * 32 + qp_c * 8);
#pragma unroll
    for (int mt = 0; mt < 4; mt++)
#pragma unroll
      for (int nt = 0; nt < 2; nt++)
        acc[mt][nt] = __builtin_amdgcn_mfma_f32_16x16x32_bf16(a[mt], b[nt], acc[mt][nt], 0, 0, 0);
  }
#pragma unroll
  for (int mt = 0; mt < 4; mt++)
#pragma unroll
    for (int nt = 0; nt < 2; nt++)
#pragma unroll
      for (int r = 0; r < 4; r++) {
        int row = m0 + mt * 16 + qv * 4 + r;
        int col = n0 + wave * 32 + nt * 16 + l15;
        outp[(long)row * RR + col] = acc[mt][nt][r];
      }
}

// ------- stage 4: z_t[kc][row'][32], row' = (bi>>2)*144 + j*4 + (bi&3) -------
// grid (8, 32), 512 threads: u/v loaded ONCE per block, bf16x8 (16 B) stores.
__launch_bounds__(512)
__global__ void k_build_z(const float* __restrict__ uc, const float* __restrict__ vc,
                          const float* __restrict__ uf, const float* __restrict__ vf,
                          const float* __restrict__ uf2, const float* __restrict__ vf2,
                          bf16* __restrict__ z) {
  __shared__ float uL[36 * 128];
  __shared__ float vL[36 * 128];
  int kq = blockIdx.x, b = blockIdx.y, tid = threadIdx.x;
  int kb = (kq & 3) * 128;
  for (int i = tid; i < 1152; i += 512) {
    int row = i >> 5, kk = (i & 31) * 4;
    long src = (long)(b * 36 + row) * RR + kb + kk;
    float4 u4, v4;
    if (kq < 4) {
      u4 = *(const float4*)(uc + src);
      v4 = *(const float4*)(vc + src);
    } else {
      float4 a1 = *(const float4*)(uf + src), a2 = *(const float4*)(uf2 + src);
      float4 b1 = *(const float4*)(vf + src), b2 = *(const float4*)(vf2 + src);
      u4.x = a1.x + a2.x; u4.y = a1.y + a2.y; u4.z = a1.z + a2.z; u4.w = a1.w + a2.w;
      v4.x = b1.x + b2.x; v4.y = b1.y + b2.y; v4.z = b1.z + b2.z; v4.w = b1.w + b2.w;
    }
    *(float4*)&uL[row * 128 + kk] = u4;
    *(float4*)&vL[row * 128 + kk] = v4;
  }
  __syncthreads();
  // 16B chunks: c -> kcl (0..3), row (0..1295), oct (0..3); kl = kcl*32 + oct*8
  for (int c = tid; c < 20736; c += 512) {
    int kcl = c / 5184;
    int rem = c - kcl * 5184;
    int row = rem >> 2;             // 0..1295 = gl*36 + j
    int oct = rem & 3;
    int gl = row / 36;
    int j = row - gl * 36;
    int kl = kcl * 32 + oct * 8;
    float4 u4a = *(const float4*)&uL[gl * 128 + kl];
    float4 u4b = *(const float4*)&uL[gl * 128 + kl + 4];
    float4 v4a = *(const float4*)&vL[j * 128 + kl];
    float4 v4b = *(const float4*)&vL[j * 128 + kl + 4];
    bf16x8 o;
    o[0] = (bf16)fmaxf(u4a.x * v4a.x, 0.f);
    o[1] = (bf16)fmaxf(u4a.y * v4a.y, 0.f);
    o[2] = (bf16)fmaxf(u4a.z * v4a.z, 0.f);
    o[3] = (bf16)fmaxf(u4a.w * v4a.w, 0.f);
    o[4] = (bf16)fmaxf(u4b.x * v4b.x, 0.f);
    o[5] = (bf16)fmaxf(u4b.y * v4b.y, 0.f);
    o[6] = (bf16)fmaxf(u4b.z * v4b.z, 0.f);
    o[7] = (bf16)fmaxf(u4b.w * v4b.w, 0.f);
    int bi = b * 36 + gl;
    long rowp = (long)(bi >> 2) * 144 + j * 4 + (bi & 3);
    *(bf16x8*)(z + ((long)(kq * 4 + kcl) * ZROWS + rowp) * 32 + oct * 8) = o;
  }
}

// ---------------- stage 5: main fused GEMM + register max + residual ----------------
// R10-proven (142 us, MfmaUtil 54%, conflicts 0, 2 blocks/CU): 16x16x32, block
// 144x256, 4 waves (wave = 144 rows x private 64 cols), A+B staged via
// global_load_lds into [row][32]+XOR-swizzle LDS, 1 barrier/kstep stage-ahead dbuf.
// Plateau notes: manual vmcnt/triple-buf (R11) neutral — backend LDS-DMA alias
// tracking re-inserts vmcnt(0); deeper buffering exceeds LDS; wider tiles exceed regs.
__launch_bounds__(256, 2)
__global__ void k_main(const bf16* __restrict__ z, const bf16* __restrict__ PTt,
                       const float* __restrict__ mm, float* __restrict__ out) {
  __shared__ bf16 lds[2 * BUFE];   // 50 KB
  int bid = blockIdx.x;
  int x = bid & 7, t = bid >> 3;
  int dt = t & 7, go = (t >> 3) * 8 + x;   // go 0..287 (4-bi groups)
  int d0 = dt * NBLK;
  int tid = threadIdx.x, wave = tid >> 6, lane = tid & 63;
  int l15 = lane & 15, qv = lane >> 4;
  int qp_c = qv ^ ((l15 >> 1) & 3);
  int qs = (lane & 3) ^ ((lane >> 3) & 3);
  int lroff = (lane >> 2) * 32 + qs * 8;

  const bf16* gA = z + (long)go * ABUF + wave * 1024 + lroff;
  const bf16* gB = PTt + (long)d0 * 32 + wave * 2048 + lroff;
  int lA = wave * 1024;
  int lB = ABUF + wave * 2048;

  int sbuf = 0;
  auto stage = [&]() {
    bf16* db = lds + sbuf * BUFE;
    gl_lds16(gA, db + lA);
    gl_lds16(gA + 512, db + lA + 512);
    if (wave == 0) gl_lds16(gA + 4096, db + 4096);
    gl_lds16(gB, db + lB);
    gl_lds16(gB + 512, db + lB + 512);
    gl_lds16(gB + 1024, db + lB + 1024);
    gl_lds16(gB + 1536, db + lB + 1536);
    gA += (long)ZROWS * 32;
    gB += 2048L * 32;
    sbuf ^= 1;
  };

  f32x4 acc[9][4] = {};
  stage();
  for (int kc = 0; kc < 32; kc++) {
    __syncthreads();
    if (kc < 31) stage();
    const bf16* cur = lds + (kc & 1) * BUFE;
    bf16x8 b[4];
#pragma unroll
    for (int nt = 0; nt < 4; nt++)
      b[nt] = *(const bf16x8*)(cur + ABUF + (wave * 64 + nt * 16 + l15) * 32 + qp_c * 8);
#pragma unroll
    for (int mt = 0; mt < 9; mt++) {
      bf16x8 av = *(const bf16x8*)(cur + (mt * 16 + l15) * 32 + qp_c * 8);
#pragma unroll
      for (int nt = 0; nt < 4; nt++)
        acc[mt][nt] = __builtin_amdgcn_mfma_f32_16x16x32_bf16(av, b[nt], acc[mt][nt], 0, 0, 0);
    }
  }

  // epilogue: row-in-block = mt*16 + qv*4 + r = j*4 + g -> g = r, j = mt*4 + qv.
#pragma unroll
  for (int nt = 0; nt < 4; nt++) {
    float mx[4];
#pragma unroll
    for (int r = 0; r < 4; r++) {
      mx[r] = acc[0][nt][r];
#pragma unroll
      for (int mt = 1; mt < 9; mt++) mx[r] = fmaxf(mx[r], acc[mt][nt][r]);
      mx[r] = fmaxf(mx[r], __shfl_xor(mx[r], 16, 64));
      mx[r] = fmaxf(mx[r], __shfl_xor(mx[r], 32, 64));
    }
    if (lane < 16) {
      int col = d0 + wave * 64 + nt * 16 + lane;
#pragma unroll
      for (int r = 0; r < 4; r++) {
        long oa = (long)(go * 4 + r) * DD + col;
        out[oa] = mx[r] + mm[oa];
      }
    }
  }
}

// ---------------- launcher ----------------
extern "C" void kernel_launch(void* const* d_in, const int* in_sizes, int n_in,
                              void* d_out, int out_size, void* d_ws, size_t ws_size,
                              hipStream_t stream) {
  const float* mm     = (const float*)d_in[0];
  const float* coords = (const float*)d_in[1];
  const float* U_feat = (const float*)d_in[2];
  const float* V_feat = (const float*)d_in[3];
  const float* P_feat = (const float*)d_in[4];
  const float* U_coord= (const float*)d_in[5];
  const float* V_coord= (const float*)d_in[6];
  const float* P_coord= (const float*)d_in[7];
  float* out = (float*)d_out;

  char* ws = (char*)d_ws;
  bf16* z   = (bf16*)(ws + 0);                 //  84,934,656 B  [kc][41472 row'][32]
  bf16* PTt = (bf16*)(ws + 84934656);          //   4,194,304 B  [kc][2048][32]
  bf16* mmb = (bf16*)(ws + 89128960);          //   4,718,592 B
  bf16* UT  = (bf16*)(ws + 93847552);          //   2,097,152 B  [512][2048]
  bf16* VT  = (bf16*)(ws + 95944704);          //   2,097,152 B
  float* uf = (float*)(ws + 98041856);         //   2,359,296 B
  float* vf = (float*)(ws + 100401152);
  float* uc = (float*)(ws + 102760448);
  float* vc = (float*)(ws + 105119744);
  float* uf2= (float*)(ws + 107479040);
  float* vf2= (float*)(ws + 109838336);        // end 112,197,632

  k_prep<<<dim3(7552), dim3(256), 0, stream>>>(mm, coords, U_feat, V_feat, P_feat,
                                               U_coord, V_coord, P_coord,
                                               mmb, UT, VT, PTt, uc, vc);
  k_gemm_uv<<<dim3(18, 4, 4), dim3(256), 0, stream>>>(mmb, UT, VT, uf, vf, uf2, vf2);
  k_build_z<<<dim3(8, 32), dim3(512), 0, stream>>>(uc, vc, uf, vf, uf2, vf2, z);
  k_main<<<dim3(2304), dim3(256), 0, stream>>>(z, PTt, mm, out);
}